// Round 14
// baseline (734.353 us; speedup 1.0000x reference)
//
#include <hip/hip_runtime.h>
#include <hip/hip_bf16.h>

#define N_AG   4096
#define T_IN   8
#define PRELEN 12
#define EDIM   64
#define HDIM   128
#define KTOT   320    // E + H (sh) + H (h)
#define GDIM   512    // 4*H
#define KI     10     // KTOT / 32
#define LOSCALE 2048.0f

typedef _Float16 f16x8 __attribute__((ext_vector_type(8)));
typedef _Float16 f16x2 __attribute__((ext_vector_type(2)));
typedef float    f32x4 __attribute__((ext_vector_type(4)));

// ---------------- workspace layout (float units) ----------------
// h      @ 0        (524288)
// c      @ 524288   (524288)
// sh     @ 1048576  (524288)
// last   @ 1572864  (8192)
// bsum   @ 1581056  (512)
// posAll @ 1581568  (57344)
// WfragH @ 1638912  (81920 floats = 163840 f16)
// WfragL @ 1720832  (81920 floats = 163840 f16)
// h16    @ 1802752  (262208 floats = 4097x128 f16, row 4096 = zeros)

// ---------------- init (round-6 verified) ----------------
__global__ __launch_bounds__(256) void init_kernel(
    const float* __restrict__ tracks,
    const float* __restrict__ Wih, const float* __restrict__ Whh,
    const float* __restrict__ bih, const float* __restrict__ bhh,
    float* __restrict__ h, float* __restrict__ c, float* __restrict__ last,
    _Float16* __restrict__ WfH, _Float16* __restrict__ WfL,
    float* __restrict__ bsum, float* __restrict__ posAll,
    float* __restrict__ h16f, float* __restrict__ out)
{
    int idx = blockIdx.x * 256 + threadIdx.x;   // grid covers 524288
    h[idx] = 0.f;
    c[idx] = 0.f;
    if (idx < 262208) h16f[idx] = 0.f;          // zero h16 (incl. pad row 4096)
    if (idx < KTOT * GDIM) {                    // pack W into MFMA fragment order, split f16
        int g = idx / KTOT, k = idx - g * KTOT;
        float val = (k < 192) ? Wih[g * 192 + k] : Whh[g * 128 + (k - 192)];
        int nt = g >> 4, ki = k >> 5;
        int ln = (g & 15) | (((k >> 3) & 3) << 4);
        int e  = k & 7;
        size_t off = (size_t)((nt * KI + ki) * 64 + ln) * 8 + e;
        _Float16 hi = (_Float16)val;
        WfH[off] = hi;
        WfL[off] = (_Float16)((val - (float)hi) * LOSCALE);
    }
    if (idx < N_AG) {                           // last = tracks[:, 7]
        last[idx * 2 + 0] = tracks[idx * 16 + 14];
        last[idx * 2 + 1] = tracks[idx * 16 + 15];
    }
    if (idx < GDIM) bsum[idx] = bih[idx] + bhh[idx];
    if (idx < 16)  out[idx] = tracks[idx];      // out[0:8] = tracks[0]
    if (idx < 7 * N_AG) {                       // posAll[t][a] = tracks[a, t]
        int t = idx / N_AG, a = idx & (N_AG - 1);
        posAll[idx * 2 + 0] = tracks[a * 16 + t * 2 + 0];
        posAll[idx * 2 + 1] = tracks[a * 16 + t * 2 + 1];
    }
}

// ---------------- social pool: float4 2-agents/lane scan + f16 gather ----------------
// 4096 blocks x 512 thr (8 waves/agent). Scan: 4 iterations, 2 ballots each
// (half the serial chain of round 6's 8). Gather: round-6 verified 4-rows/inst.
__global__ __launch_bounds__(512) void social_pool(
    const float* __restrict__ pos,      // compact N x 2
    const _Float16* __restrict__ h16,   // 4097 x 128 f16 (row 4096 = zeros)
    float* __restrict__ sh)             // N x 128 (f32)
{
    __shared__ unsigned short idxbuf[8][520];   // 8.3 KB neighbor lists (+pad)
    __shared__ float red[8][4][HDIM];           // 16 KB
    int i    = blockIdx.x;
    int lane = threadIdx.x & 63;
    int wv   = threadIdx.x >> 6;        // 0..7
    const float2* posv = (const float2*)pos;
    float2 pi = posv[i];
    unsigned long long ltmask = (1ull << lane) - 1ull;

    // ---- phase 1: scan, 2 candidates per lane per iteration ----
    float4 q[4];
#pragma unroll
    for (int cc = 0; cc < 4; cc++) {
        int base = wv * 128 + cc * 1024;        // wave covers 4x128 interleaved
        q[cc] = *(const float4*)(pos + (size_t)(base + 2 * lane) * 2);
    }
    int cnt = 0;
#pragma unroll
    for (int cc = 0; cc < 4; cc++) {
        int base = wv * 128 + cc * 1024;
        float dx0 = q[cc].x - pi.x, dy0 = q[cc].y - pi.y;
        float dx1 = q[cc].z - pi.x, dy1 = q[cc].w - pi.y;
        bool p0 = (dx0 * dx0 + dy0 * dy0 < 25.0f);
        bool p1 = (dx1 * dx1 + dy1 * dy1 < 25.0f);
        unsigned long long m0 = __ballot(p0);
        unsigned long long m1 = __ballot(p1);
        if (p0) idxbuf[wv][cnt + __popcll(m0 & ltmask)] =
                    (unsigned short)(base + 2 * lane);
        cnt += __popcll(m0);
        if (p1) idxbuf[wv][cnt + __popcll(m1 & ltmask)] =
                    (unsigned short)(base + 2 * lane + 1);
        cnt += __popcll(m1);
    }
    int cpad = (cnt + 7) & ~7;                  // pad with zero-row index
    if (lane < cpad - cnt) idxbuf[wv][cnt + lane] = (unsigned short)N_AG;

    // ---- phase 2: gather-sum; lane group (lane>>4) takes row t+grp; 16B/lane ----
    int grp = lane >> 4, sub = lane & 15;
    float accA[8] = {0,0,0,0,0,0,0,0};
    float accB[8] = {0,0,0,0,0,0,0,0};
    for (int t = 0; t < cpad; t += 8) {
        int ja = idxbuf[wv][t + grp];
        int jb = idxbuf[wv][t + 4 + grp];
        f16x8 va = *(const f16x8*)(h16 + (size_t)ja * HDIM + sub * 8);
        f16x8 vb = *(const f16x8*)(h16 + (size_t)jb * HDIM + sub * 8);
#pragma unroll
        for (int e = 0; e < 8; e++) accA[e] += (float)va[e];
#pragma unroll
        for (int e = 0; e < 8; e++) accB[e] += (float)vb[e];
    }
#pragma unroll
    for (int e = 0; e < 8; e++) accA[e] += accB[e];
    *(f32x4*)&red[wv][grp][sub * 8]     = *(f32x4*)&accA[0];
    *(f32x4*)&red[wv][grp][sub * 8 + 4] = *(f32x4*)&accA[4];
    __syncthreads();

    int tt = threadIdx.x;
    if (tt < HDIM) {
        float s = 0.f;
#pragma unroll
        for (int w = 0; w < 8; w++)
#pragma unroll
            for (int g = 0; g < 4; g++)
                s += red[w][g][tt];
        sh[(unsigned)i * HDIM + tt] = s;
    }
}

// ---------------- fused MFMA gates GEMM + LSTM update ----------------
// block: 32 agents x 1/4 of dcols. 512 blocks x 256 thr (4 waves), 40KB LDS
// -> 4 blocks/CU co-resident (4 waves/SIMD) to hide L2 weight-load latency.
// wave w: m-tile (w&1), n-group ng=(w>>1); ntiles {n0,n0+8,n0+16,n0+24} =
// i,f,g,o for its 16 dcols -> pointwise update in registers.
__global__ __launch_bounds__(256) void lstm_step(
    const float* __restrict__ pos,      // compact N x 2
    const float* __restrict__ sh,       // N x 128
    const float* __restrict__ We, const float* __restrict__ be,
    const _Float16* __restrict__ WfH,   // [32 nt][10 ki][64 ln][8] f16 hi
    const _Float16* __restrict__ WfL,   // same, lo*2048
    const float* __restrict__ bsum,
    float* __restrict__ h, float* __restrict__ c,
    _Float16* __restrict__ h16,         // f16 shadow of h for pooling
    int firstStep)
{
    __shared__ __align__(16) _Float16 AH[2 * KI][64][8];   // 20 KB
    __shared__ __align__(16) _Float16 AL[2 * KI][64][8];   // 20 KB
    int cg  = blockIdx.x & 3;
    int a0  = (blockIdx.x >> 2) * 32;
    int tid = threadIdx.x;

    // ---- stage x = [emb(pos) | sh | h] for 32 agents as split-f16 fragments ----
    for (int u = tid; u < 32 * (KTOT / 8); u += 256) {  // 1280 units
        int a = u / 40, kg = u - a * 40;
        int ga = a0 + a;
        int k0 = kg * 8;
        float v[8];
        if (k0 < EDIM) {
            float px = pos[ga * 2], py = pos[ga * 2 + 1];
#pragma unroll
            for (int j = 0; j < 8; j++) {
                int k = k0 + j;
                v[j] = fmaf(px, We[k * 2], fmaf(py, We[k * 2 + 1], be[k]));
            }
        } else if (k0 < EDIM + HDIM) {
#pragma unroll
            for (int j = 0; j < 8; j++)
                v[j] = firstStep ? 0.f : sh[(unsigned)ga * HDIM + (k0 - EDIM + j)];
        } else {
#pragma unroll
            for (int j = 0; j < 8; j++)
                v[j] = h[(unsigned)ga * HDIM + (k0 - EDIM - HDIM + j)];
        }
        f16x8 hi8, lo8;
#pragma unroll
        for (int j = 0; j < 8; j++) {
            _Float16 hv = (_Float16)v[j];
            hi8[j] = hv;
            lo8[j] = (_Float16)((v[j] - (float)hv) * LOSCALE);
        }
        int m = a >> 4, ki = kg >> 2, ln = (a & 15) | ((kg & 3) << 4);
        *(f16x8*)&AH[m * KI + ki][ln][0] = hi8;
        *(f16x8*)&AL[m * KI + ki][ln][0] = lo8;
    }
    __syncthreads();

    int wave = tid >> 6, lane = tid & 63;
    int m  = wave & 1;
    int ng = wave >> 1;
    int n0 = 2 * cg + ng;
    int dcol = 32 * cg + 16 * ng + (lane & 15);

    f32x4 acc[4], accL[4];
#pragma unroll
    for (int g = 0; g < 4; g++) {
        float bb = bsum[dcol + g * 128];
        f32x4 z; z[0] = bb; z[1] = bb; z[2] = bb; z[3] = bb;
        acc[g] = z;
        f32x4 zz; zz[0] = 0.f; zz[1] = 0.f; zz[2] = 0.f; zz[3] = 0.f;
        accL[g] = zz;
    }

#pragma unroll
    for (int ki = 0; ki < KI; ki++) {
        f16x8 ah = *(const f16x8*)&AH[m * KI + ki][lane][0];
        f16x8 al = *(const f16x8*)&AL[m * KI + ki][lane][0];
#pragma unroll
        for (int g = 0; g < 4; g++) {
            int nt = n0 + 8 * g;
            size_t off = (size_t)((nt * KI + ki) * 64 + lane) * 8;
            f16x8 bh = *(const f16x8*)&WfH[off];
            f16x8 bl = *(const f16x8*)&WfL[off];
            acc[g]  = __builtin_amdgcn_mfma_f32_16x16x32_f16(ah, bh, acc[g],  0, 0, 0);
            accL[g] = __builtin_amdgcn_mfma_f32_16x16x32_f16(al, bh, accL[g], 0, 0, 0);
            accL[g] = __builtin_amdgcn_mfma_f32_16x16x32_f16(ah, bl, accL[g], 0, 0, 0);
        }
    }

    // ---- LSTM pointwise update, fully in registers ----
    const float inv = 1.0f / LOSCALE;
#pragma unroll
    for (int r = 0; r < 4; r++) {
        int alc = (lane >> 4) * 4 + r;      // row within m-tile (C/D mapping)
        int ga  = a0 + 16 * m + alc;
        float vi = fmaf(accL[0][r], inv, acc[0][r]);
        float vf = fmaf(accL[1][r], inv, acc[1][r]);
        float vg = fmaf(accL[2][r], inv, acc[2][r]);
        float vo = fmaf(accL[3][r], inv, acc[3][r]);
        float ig = 1.f / (1.f + expf(-vi));
        float fg = 1.f / (1.f + expf(-vf));
        float gg = tanhf(vg);
        float og = 1.f / (1.f + expf(-vo));
        float cold = c[(unsigned)ga * HDIM + dcol];
        float cn = fmaf(fg, cold, ig * gg);
        float hn = og * tanhf(cn);
        c[(unsigned)ga * HDIM + dcol] = cn;
        h[(unsigned)ga * HDIM + dcol] = hn;
        h16[(unsigned)ga * HDIM + dcol] = (_Float16)hn;   // f16 shadow for pool
    }
}

// ---------------- decoder tail: delta = h@Wd^T + bd; last += delta ----------------
__global__ __launch_bounds__(256) void decode_step(
    const float* __restrict__ h, const float* __restrict__ Wd,
    const float* __restrict__ bd, float* __restrict__ last,
    float* __restrict__ out, int step)
{
    int a    = blockIdx.x * 4 + (threadIdx.x >> 6);
    int lane = threadIdx.x & 63;
    const float* hr = h + (unsigned)a * HDIM;
    float h0 = hr[lane], h1 = hr[lane + 64];
    float dx = fmaf(h0, Wd[lane],       h1 * Wd[lane + 64]);
    float dy = fmaf(h0, Wd[128 + lane], h1 * Wd[192 + lane]);
#pragma unroll
    for (int off = 32; off; off >>= 1) {
        dx += __shfl_down(dx, off);
        dy += __shfl_down(dy, off);
    }
    if (lane == 0) {
        float lx = last[a * 2 + 0] + dx + bd[0];
        float ly = last[a * 2 + 1] + dy + bd[1];
        last[a * 2 + 0] = lx;
        last[a * 2 + 1] = ly;
        if (a == 0) {
            out[(8 + step) * 2 + 0] = lx;
            out[(8 + step) * 2 + 1] = ly;
        }
    }
}

extern "C" void kernel_launch(void* const* d_in, const int* in_sizes, int n_in,
                              void* d_out, int out_size, void* d_ws, size_t ws_size,
                              hipStream_t stream)
{
    const float* tracks = (const float*)d_in[0];
    const float* We     = (const float*)d_in[1];
    const float* be     = (const float*)d_in[2];
    const float* Wih    = (const float*)d_in[3];
    const float* Whh    = (const float*)d_in[4];
    const float* bih    = (const float*)d_in[5];
    const float* bhh    = (const float*)d_in[6];
    const float* Wd     = (const float*)d_in[7];
    const float* bd     = (const float*)d_in[8];
    float* out = (float*)d_out;
    float* ws  = (float*)d_ws;

    float*     h      = ws;
    float*     c      = ws + 524288;
    float*     sh     = ws + 1048576;
    float*     last   = ws + 1572864;
    float*     bsum   = ws + 1581056;
    float*     posAll = ws + 1581568;
    _Float16*  WfH    = (_Float16*)(ws + 1638912);
    _Float16*  WfL    = (_Float16*)(ws + 1720832);
    float*     h16f   = ws + 1802752;
    _Float16*  h16    = (_Float16*)h16f;

    init_kernel<<<2048, 256, 0, stream>>>(tracks, Wih, Whh, bih, bhh,
                                          h, c, last, WfH, WfL, bsum, posAll,
                                          h16f, out);

    // step 0: x0 = [emb(tracks[:,0]) | zeros], h=c=0
    lstm_step<<<512, 256, 0, stream>>>(posAll, sh, We, be, WfH, WfL, bsum,
                                       h, c, h16, 1);

    // encoder: t = 0..6
    for (int t = 0; t < T_IN - 1; t++) {
        const float* pos = posAll + (size_t)t * N_AG * 2;
        social_pool<<<N_AG, 512, 0, stream>>>(pos, h16, sh);
        lstm_step<<<512, 256, 0, stream>>>(pos, sh, We, be, WfH, WfL, bsum,
                                           h, c, h16, 0);
    }

    // decoder: 12 steps
    for (int s = 0; s < PRELEN; s++) {
        social_pool<<<N_AG, 512, 0, stream>>>(last, h16, sh);
        lstm_step<<<512, 256, 0, stream>>>(last, sh, We, be, WfH, WfL, bsum,
                                           h, c, h16, 0);
        decode_step<<<N_AG / 4, 256, 0, stream>>>(h, Wd, bd, last, out, s);
    }
}

// Round 15
// 637.228 us; speedup vs baseline: 1.1524x; 1.1524x over previous
//
#include <hip/hip_runtime.h>
#include <hip/hip_bf16.h>

#define N_AG   4096
#define T_IN   8
#define PRELEN 12
#define EDIM   64
#define HDIM   128
#define KTOT   320    // E + H (sh) + H (h)
#define GDIM   512    // 4*H
#define KI     10     // KTOT / 32
#define LOSCALE 2048.0f

typedef _Float16 f16x8 __attribute__((ext_vector_type(8)));
typedef _Float16 f16x2 __attribute__((ext_vector_type(2)));
typedef float    f32x4 __attribute__((ext_vector_type(4)));

// ---------------- workspace layout (float units) ----------------
// hA     @ 0        (524288)   h double buffer (f32)
// hB     @ 524288   (524288)
// c      @ 1048576  (524288)   block-private -> single buffer
// lastA  @ 1572864  (8192)     last double buffer
// lastB  @ 1581056  (8192)
// bsum   @ 1589248  (512)
// posAll @ 1589760  (57344)
// WfH    @ 1647104  (81920 floats = 163840 f16)
// WfL    @ 1729024  (81920 floats = 163840 f16)
// h16A   @ 1810944  (262208 floats = 4097x128 f16, row 4096 = zeros)
// h16B   @ 2073152  (262208)
// total ~2.34M floats ≈ 9.3 MB

// ---------------- init ----------------
__global__ __launch_bounds__(256) void init_kernel(
    const float* __restrict__ tracks,
    const float* __restrict__ Wih, const float* __restrict__ Whh,
    const float* __restrict__ bih, const float* __restrict__ bhh,
    float* __restrict__ hA, float* __restrict__ hB, float* __restrict__ c,
    float* __restrict__ lastA, float* __restrict__ lastB,
    _Float16* __restrict__ WfH, _Float16* __restrict__ WfL,
    float* __restrict__ bsum, float* __restrict__ posAll,
    float* __restrict__ h16Af, float* __restrict__ h16Bf,
    float* __restrict__ out)
{
    int idx = blockIdx.x * 256 + threadIdx.x;   // grid covers 524288
    hA[idx] = 0.f;
    hB[idx] = 0.f;
    c[idx]  = 0.f;
    if (idx < 262208) { h16Af[idx] = 0.f; h16Bf[idx] = 0.f; }  // incl. pad row
    if (idx < KTOT * GDIM) {                    // pack W into MFMA fragment order, split f16
        int g = idx / KTOT, k = idx - g * KTOT;
        float val = (k < 192) ? Wih[g * 192 + k] : Whh[g * 128 + (k - 192)];
        int nt = g >> 4, ki = k >> 5;
        int ln = (g & 15) | (((k >> 3) & 3) << 4);
        int e  = k & 7;
        size_t off = (size_t)((nt * KI + ki) * 64 + ln) * 8 + e;
        _Float16 hi = (_Float16)val;
        WfH[off] = hi;
        WfL[off] = (_Float16)((val - (float)hi) * LOSCALE);
    }
    if (idx < N_AG) {                           // last = tracks[:, 7]
        lastA[idx * 2 + 0] = tracks[idx * 16 + 14];
        lastA[idx * 2 + 1] = tracks[idx * 16 + 15];
        lastB[idx * 2 + 0] = 0.f;
        lastB[idx * 2 + 1] = 0.f;
    }
    if (idx < GDIM) bsum[idx] = bih[idx] + bhh[idx];
    if (idx < 16)  out[idx] = tracks[idx];      // out[0:8] = tracks[0]
    if (idx < 7 * N_AG) {                       // posAll[t][a] = tracks[a, t]
        int t = idx / N_AG, a = idx & (N_AG - 1);
        posAll[idx * 2 + 0] = tracks[a * 16 + t * 2 + 0];
        posAll[idx * 2 + 1] = tracks[a * 16 + t * 2 + 1];
    }
}

// ---------------- fused per-step kernel: pool -> gates GEMM -> LSTM -> decode ----------------
// 256 blocks x 512 thr. Block owns 16 agents x ALL 512 gate cols (r2 geometry):
// wave w owns ntiles {w, w+8, w+16, w+24} = i,f,g,o of dcols [w*16, w*16+16).
// Pool computed in-block into LDS (no global sh). h/h16/last double-buffered
// by step parity so no buffer is both read and written within one launch.
__global__ __launch_bounds__(512) void social_step(
    const float* __restrict__ pp,       // positions for pool+emb (posAll[t] or lastIn)
    const float* __restrict__ We, const float* __restrict__ be,
    const _Float16* __restrict__ WfH, const _Float16* __restrict__ WfL,
    const float* __restrict__ bsum,
    const float* __restrict__ hIn, float* __restrict__ hOut,
    const _Float16* __restrict__ h16In, _Float16* __restrict__ h16Out,
    float* __restrict__ c,
    const float* __restrict__ lastIn, float* __restrict__ lastOut,
    const float* __restrict__ Wd, const float* __restrict__ bd,
    float* __restrict__ out,
    int firstStep, int decStep)
{
    __shared__ __align__(16) char smraw[45056];
    _Float16 (*AH)[64][8] = (_Float16(*)[64][8])smraw;              // 10 KB [KI][64][8]
    _Float16 (*AL)[64][8] = (_Float16(*)[64][8])(smraw + 10240);    // 10 KB
    float (*shs)[HDIM]    = (float(*)[HDIM])(smraw + 20480);        //  8 KB [16][128]
    unsigned short (*sidx)[2][512] = (unsigned short(*)[2][512])(smraw + 28672); // 16 KB
    float (*hs)[HDIM]     = (float(*)[HDIM])(smraw + 28672);        //  8 KB (aliases sidx)

    int tid  = threadIdx.x;
    int lane = tid & 63;
    int wv   = tid >> 6;                 // 0..7
    int a0   = blockIdx.x * 16;

    // ---- pool phase: wave wv covers agents a0+2wv, a0+2wv+1 ----
    if (!firstStep) {
        const float2* pv = (const float2*)pp;
        int iA = a0 + 2 * wv, iB = iA + 1;
        float2 piA = pv[iA], piB = pv[iB];
        unsigned long long ltmask = (1ull << lane) - 1ull;
        int cntA = 0, cntB = 0;
#pragma unroll 4
        for (int cc = 0; cc < 32; cc++) {        // 128 candidates/iter, shared loads
            int j0 = cc * 128 + 2 * lane;
            float4 q = *(const float4*)(pp + (size_t)j0 * 2);
            float dxA0 = q.x - piA.x, dyA0 = q.y - piA.y;
            float dxA1 = q.z - piA.x, dyA1 = q.w - piA.y;
            float dxB0 = q.x - piB.x, dyB0 = q.y - piB.y;
            float dxB1 = q.z - piB.x, dyB1 = q.w - piB.y;
            bool pA0 = dxA0 * dxA0 + dyA0 * dyA0 < 25.0f;
            bool pA1 = dxA1 * dxA1 + dyA1 * dyA1 < 25.0f;
            bool pB0 = dxB0 * dxB0 + dyB0 * dyB0 < 25.0f;
            bool pB1 = dxB1 * dxB1 + dyB1 * dyB1 < 25.0f;
            unsigned long long mA0 = __ballot(pA0), mA1 = __ballot(pA1);
            unsigned long long mB0 = __ballot(pB0), mB1 = __ballot(pB1);
            if (pA0) { int s = cntA + __popcll(mA0 & ltmask); if (s < 512) sidx[wv][0][s] = (unsigned short)j0; }
            cntA += __popcll(mA0);
            if (pA1) { int s = cntA + __popcll(mA1 & ltmask); if (s < 512) sidx[wv][0][s] = (unsigned short)(j0 + 1); }
            cntA += __popcll(mA1);
            if (pB0) { int s = cntB + __popcll(mB0 & ltmask); if (s < 512) sidx[wv][1][s] = (unsigned short)j0; }
            cntB += __popcll(mB0);
            if (pB1) { int s = cntB + __popcll(mB1 & ltmask); if (s < 512) sidx[wv][1][s] = (unsigned short)(j0 + 1); }
            cntB += __popcll(mB1);
        }
        if (cntA > 512) cntA = 512;
        if (cntB > 512) cntB = 512;
        int cpadA = (cntA + 7) & ~7, cpadB = (cntB + 7) & ~7;
        if (lane < cpadA - cntA) sidx[wv][0][cntA + lane] = (unsigned short)N_AG;
        if (lane < cpadB - cntB) sidx[wv][1][cntB + lane] = (unsigned short)N_AG;

        int d0 = lane * 2;
#pragma unroll
        for (int rep = 0; rep < 2; rep++) {      // r10-verified 8-deep f16 gather
            int cpad = rep ? cpadB : cpadA;
            float s0 = 0.f, s1 = 0.f;
            for (int t2 = 0; t2 < cpad; t2 += 8) {
                f16x2 v[8];
#pragma unroll
                for (int r = 0; r < 8; r++) {
                    int j = sidx[wv][rep][t2 + r];
                    v[r] = *(const f16x2*)(h16In + (size_t)j * HDIM + d0);
                }
#pragma unroll
                for (int r = 0; r < 8; r++) { s0 += (float)v[r][0]; s1 += (float)v[r][1]; }
            }
            shs[2 * wv + rep][d0]     = s0;
            shs[2 * wv + rep][d0 + 1] = s1;
        }
    }
    __syncthreads();

    // ---- stage x = [emb(pp) | shs | hIn] as split-f16 fragments (r2 geometry) ----
    for (int u = tid; u < 16 * (KTOT / 8); u += 512) {   // 640 units
        int a = u & 15, kg = u >> 4;
        int ga = a0 + a;
        int k0 = kg * 8;
        float v[8];
        if (k0 < EDIM) {
            float px = pp[ga * 2], py = pp[ga * 2 + 1];
#pragma unroll
            for (int j = 0; j < 8; j++) {
                int k = k0 + j;
                v[j] = fmaf(px, We[k * 2], fmaf(py, We[k * 2 + 1], be[k]));
            }
        } else if (k0 < EDIM + HDIM) {
#pragma unroll
            for (int j = 0; j < 8; j++)
                v[j] = firstStep ? 0.f : shs[a][k0 - EDIM + j];
        } else {
#pragma unroll
            for (int j = 0; j < 8; j++)
                v[j] = hIn[(unsigned)ga * HDIM + (k0 - EDIM - HDIM + j)];
        }
        f16x8 hi8, lo8;
#pragma unroll
        for (int j = 0; j < 8; j++) {
            _Float16 hv = (_Float16)v[j];
            hi8[j] = hv;
            lo8[j] = (_Float16)((v[j] - (float)hv) * LOSCALE);
        }
        int ki = kg >> 2, ln = a | ((kg & 3) << 4);
        *(f16x8*)&AH[ki][ln][0] = hi8;
        *(f16x8*)&AL[ki][ln][0] = lo8;
    }
    __syncthreads();

    // ---- MFMA gates GEMM: wave wv owns ntiles {wv, wv+8, wv+16, wv+24} ----
    int dcol = wv * 16 + (lane & 15);

    f32x4 acc[4], accL[4];
#pragma unroll
    for (int g = 0; g < 4; g++) {
        float bb = bsum[dcol + g * 128];
        f32x4 z; z[0] = bb; z[1] = bb; z[2] = bb; z[3] = bb;
        acc[g] = z;
        f32x4 zz; zz[0] = 0.f; zz[1] = 0.f; zz[2] = 0.f; zz[3] = 0.f;
        accL[g] = zz;
    }
#pragma unroll
    for (int ki = 0; ki < KI; ki++) {
        f16x8 ah = *(const f16x8*)&AH[ki][lane][0];
        f16x8 al = *(const f16x8*)&AL[ki][lane][0];
#pragma unroll
        for (int g = 0; g < 4; g++) {
            int nt = wv + 8 * g;
            size_t off = (size_t)((nt * KI + ki) * 64 + lane) * 8;
            f16x8 bh = *(const f16x8*)&WfH[off];
            f16x8 bl = *(const f16x8*)&WfL[off];
            acc[g]  = __builtin_amdgcn_mfma_f32_16x16x32_f16(ah, bh, acc[g],  0, 0, 0);
            accL[g] = __builtin_amdgcn_mfma_f32_16x16x32_f16(al, bh, accL[g], 0, 0, 0);
            accL[g] = __builtin_amdgcn_mfma_f32_16x16x32_f16(ah, bl, accL[g], 0, 0, 0);
        }
    }

    // ---- LSTM pointwise update in registers; write hOut/h16Out, hs to LDS ----
    const float inv = 1.0f / LOSCALE;
#pragma unroll
    for (int r = 0; r < 4; r++) {
        int alc = (lane >> 4) * 4 + r;      // C/D row mapping
        int ga  = a0 + alc;
        float vi = fmaf(accL[0][r], inv, acc[0][r]);
        float vf = fmaf(accL[1][r], inv, acc[1][r]);
        float vg = fmaf(accL[2][r], inv, acc[2][r]);
        float vo = fmaf(accL[3][r], inv, acc[3][r]);
        float ig = 1.f / (1.f + expf(-vi));
        float fg = 1.f / (1.f + expf(-vf));
        float gg = tanhf(vg);
        float og = 1.f / (1.f + expf(-vo));
        float cold = c[(unsigned)ga * HDIM + dcol];
        float cn = fmaf(fg, cold, ig * gg);
        float hn = og * tanhf(cn);
        c[(unsigned)ga * HDIM + dcol]      = cn;
        hOut[(unsigned)ga * HDIM + dcol]   = hn;
        h16Out[(unsigned)ga * HDIM + dcol] = (_Float16)hn;
        hs[alc][dcol] = hn;                 // for fused decode (aliases sidx)
    }

    // ---- fused decoder tail: delta = h_new@Wd^T + bd; lastOut = lastIn + delta ----
    if (decStep >= 0) {
        __syncthreads();
        int ag = tid >> 5, comp = (tid >> 4) & 1, l16 = tid & 15;
        float s = 0.f;
#pragma unroll
        for (int j = 0; j < 8; j++) {
            int d = l16 * 8 + j;
            s += hs[ag][d] * Wd[comp * HDIM + d];
        }
        s += __shfl_down(s, 8, 16);
        s += __shfl_down(s, 4, 16);
        s += __shfl_down(s, 2, 16);
        s += __shfl_down(s, 1, 16);
        if (l16 == 0) {
            int ga = a0 + ag;
            float nl = lastIn[ga * 2 + comp] + s + bd[comp];
            lastOut[ga * 2 + comp] = nl;
            if (ga == 0) out[(8 + decStep) * 2 + comp] = nl;
        }
    }
}

extern "C" void kernel_launch(void* const* d_in, const int* in_sizes, int n_in,
                              void* d_out, int out_size, void* d_ws, size_t ws_size,
                              hipStream_t stream)
{
    const float* tracks = (const float*)d_in[0];
    const float* We     = (const float*)d_in[1];
    const float* be     = (const float*)d_in[2];
    const float* Wih    = (const float*)d_in[3];
    const float* Whh    = (const float*)d_in[4];
    const float* bih    = (const float*)d_in[5];
    const float* bhh    = (const float*)d_in[6];
    const float* Wd     = (const float*)d_in[7];
    const float* bd     = (const float*)d_in[8];
    float* out = (float*)d_out;
    float* ws  = (float*)d_ws;

    float*     hA     = ws;
    float*     hB     = ws + 524288;
    float*     c      = ws + 1048576;
    float*     lastA  = ws + 1572864;
    float*     lastB  = ws + 1581056;
    float*     bsum   = ws + 1589248;
    float*     posAll = ws + 1589760;
    _Float16*  WfH    = (_Float16*)(ws + 1647104);
    _Float16*  WfL    = (_Float16*)(ws + 1729024);
    float*     h16Af  = ws + 1810944;
    float*     h16Bf  = ws + 2073152;

    float*    hbuf[2]   = { hA, hB };
    _Float16* h16buf[2] = { (_Float16*)h16Af, (_Float16*)h16Bf };
    float*    lbuf[2]   = { lastA, lastB };

    init_kernel<<<2048, 256, 0, stream>>>(tracks, Wih, Whh, bih, bhh,
                                          hA, hB, c, lastA, lastB,
                                          WfH, WfL, bsum, posAll,
                                          h16Af, h16Bf, out);

    int k = 0;   // step counter: step k reads buf[(k+1)&1], writes buf[k&1]
    auto step = [&](const float* pp, const float* lin, float* lout,
                    int fs, int ds) {
        social_step<<<256, 512, 0, stream>>>(
            pp, We, be, WfH, WfL, bsum,
            hbuf[(k + 1) & 1], hbuf[k & 1],
            h16buf[(k + 1) & 1], h16buf[k & 1],
            c, lin, lout, Wd, bd, out, fs, ds);
        k++;
    };

    // step 0: x0 = [emb(tracks[:,0]) | zeros], h=c=0
    step(posAll, nullptr, nullptr, 1, -1);

    // encoder: t = 0..6 (pool over posAll[t], emb(posAll[t]))
    for (int t = 0; t < T_IN - 1; t++)
        step(posAll + (size_t)t * N_AG * 2, nullptr, nullptr, 0, -1);

    // decoder: 12 steps (pool+emb over lastIn; decode writes lastOut)
    for (int s = 0; s < PRELEN; s++)
        step(lbuf[s & 1], lbuf[s & 1], lbuf[(s + 1) & 1], 0, s);
}

// Round 16
// 509.133 us; speedup vs baseline: 1.4424x; 1.2516x over previous
//
#include <hip/hip_runtime.h>
#include <hip/hip_bf16.h>

#define N_AG   4096
#define T_IN   8
#define PRELEN 12
#define EDIM   64
#define HDIM   128
#define KTOT   320    // E + H (sh) + H (h)
#define GDIM   512    // 4*H
#define KI     10     // KTOT / 32
#define LOSCALE 2048.0f

typedef _Float16 f16x8 __attribute__((ext_vector_type(8)));
typedef _Float16 f16x2 __attribute__((ext_vector_type(2)));
typedef float    f32x4 __attribute__((ext_vector_type(4)));

// ---------------- workspace layout (float units) ----------------
// hA     @ 0        (524288)   h double buffer (f32)
// hB     @ 524288   (524288)
// c      @ 1048576  (524288)   block-private -> single buffer
// lastA  @ 1572864  (8192)     last double buffer
// lastB  @ 1581056  (8192)
// bsum   @ 1589248  (512)
// posAll @ 1589760  (57344)
// WfH    @ 1647104  (81920 floats = 163840 f16)
// WfL    @ 1729024  (81920 floats = 163840 f16)
// h16A   @ 1810944  (262208 floats = 4097x128 f16, row 4096 = zeros)
// h16B   @ 2073152  (262208)

// ---------------- init (r14/r15 verified) ----------------
__global__ __launch_bounds__(256) void init_kernel(
    const float* __restrict__ tracks,
    const float* __restrict__ Wih, const float* __restrict__ Whh,
    const float* __restrict__ bih, const float* __restrict__ bhh,
    float* __restrict__ hA, float* __restrict__ hB, float* __restrict__ c,
    float* __restrict__ lastA, float* __restrict__ lastB,
    _Float16* __restrict__ WfH, _Float16* __restrict__ WfL,
    float* __restrict__ bsum, float* __restrict__ posAll,
    float* __restrict__ h16Af, float* __restrict__ h16Bf,
    float* __restrict__ out)
{
    int idx = blockIdx.x * 256 + threadIdx.x;   // grid covers 524288
    hA[idx] = 0.f;
    hB[idx] = 0.f;
    c[idx]  = 0.f;
    if (idx < 262208) { h16Af[idx] = 0.f; h16Bf[idx] = 0.f; }  // incl. pad row
    if (idx < KTOT * GDIM) {                    // pack W into MFMA fragment order, split f16
        int g = idx / KTOT, k = idx - g * KTOT;
        float val = (k < 192) ? Wih[g * 192 + k] : Whh[g * 128 + (k - 192)];
        int nt = g >> 4, ki = k >> 5;
        int ln = (g & 15) | (((k >> 3) & 3) << 4);
        int e  = k & 7;
        size_t off = (size_t)((nt * KI + ki) * 64 + ln) * 8 + e;
        _Float16 hi = (_Float16)val;
        WfH[off] = hi;
        WfL[off] = (_Float16)((val - (float)hi) * LOSCALE);
    }
    if (idx < N_AG) {                           // last = tracks[:, 7]
        lastA[idx * 2 + 0] = tracks[idx * 16 + 14];
        lastA[idx * 2 + 1] = tracks[idx * 16 + 15];
        lastB[idx * 2 + 0] = 0.f;
        lastB[idx * 2 + 1] = 0.f;
    }
    if (idx < GDIM) bsum[idx] = bih[idx] + bhh[idx];
    if (idx < 16)  out[idx] = tracks[idx];      // out[0:8] = tracks[0]
    if (idx < 7 * N_AG) {                       // posAll[t][a] = tracks[a, t]
        int t = idx / N_AG, a = idx & (N_AG - 1);
        posAll[idx * 2 + 0] = tracks[a * 16 + t * 2 + 0];
        posAll[idx * 2 + 1] = tracks[a * 16 + t * 2 + 1];
    }
}

// ---------------- fused per-step kernel: pool -> gates GEMM -> LSTM -> decode ----------------
// 256 blocks x 512 thr. Block owns 16 agents x ALL 512 gate cols.
// Pool: positions staged in LDS (scan chain reads LDS, not L2); 16-deep gather.
// h/h16/last double-buffered by step parity (r15 verified).
__global__ __launch_bounds__(512) void social_step(
    const float* __restrict__ pp,       // positions for pool+emb (posAll[t] or lastIn)
    const float* __restrict__ We, const float* __restrict__ be,
    const _Float16* __restrict__ WfH, const _Float16* __restrict__ WfL,
    const float* __restrict__ bsum,
    const float* __restrict__ hIn, float* __restrict__ hOut,
    const _Float16* __restrict__ h16In, _Float16* __restrict__ h16Out,
    float* __restrict__ c,
    const float* __restrict__ lastIn, float* __restrict__ lastOut,
    const float* __restrict__ Wd, const float* __restrict__ bd,
    float* __restrict__ out,
    int firstStep, int decStep)
{
    __shared__ __align__(16) char smraw[77824];
    _Float16 (*AH)[64][8] = (_Float16(*)[64][8])smraw;              // 10 KB [KI][64][8]
    _Float16 (*AL)[64][8] = (_Float16(*)[64][8])(smraw + 10240);    // 10 KB
    float (*shs)[HDIM]    = (float(*)[HDIM])(smraw + 20480);        //  8 KB [16][128]
    unsigned short (*sidx)[2][512] = (unsigned short(*)[2][512])(smraw + 28672); // 16 KB
    float (*hs)[HDIM]     = (float(*)[HDIM])(smraw + 28672);        //  8 KB (aliases sidx)
    float* posl           = (float*)(smraw + 45056);                // 32 KB [4096][2]

    int tid  = threadIdx.x;
    int lane = tid & 63;
    int wv   = tid >> 6;                 // 0..7
    int a0   = blockIdx.x * 16;

    // ---- pool phase: wave wv covers agents a0+2wv, a0+2wv+1 ----
    if (!firstStep) {
        // stage all positions into LDS (coalesced float4: 512 thr x 4 x 16B = 32KB)
#pragma unroll
        for (int k = 0; k < 4; k++) {
            int u = tid + k * 512;
            *(f32x4*)&posl[u * 4] = *(const f32x4*)(pp + (size_t)u * 4);
        }
        __syncthreads();

        const float2* pvl = (const float2*)posl;
        int iA = a0 + 2 * wv, iB = iA + 1;
        float2 piA = pvl[iA], piB = pvl[iB];
        unsigned long long ltmask = (1ull << lane) - 1ull;
        int cntA = 0, cntB = 0;
#pragma unroll 8
        for (int cc = 0; cc < 32; cc++) {        // scan from LDS: chain is ballot-bound
            int j0 = cc * 128 + 2 * lane;
            float4 q = *(const float4*)&posl[(size_t)j0 * 2];
            float dxA0 = q.x - piA.x, dyA0 = q.y - piA.y;
            float dxA1 = q.z - piA.x, dyA1 = q.w - piA.y;
            float dxB0 = q.x - piB.x, dyB0 = q.y - piB.y;
            float dxB1 = q.z - piB.x, dyB1 = q.w - piB.y;
            bool pA0 = dxA0 * dxA0 + dyA0 * dyA0 < 25.0f;
            bool pA1 = dxA1 * dxA1 + dyA1 * dyA1 < 25.0f;
            bool pB0 = dxB0 * dxB0 + dyB0 * dyB0 < 25.0f;
            bool pB1 = dxB1 * dxB1 + dyB1 * dyB1 < 25.0f;
            unsigned long long mA0 = __ballot(pA0), mA1 = __ballot(pA1);
            unsigned long long mB0 = __ballot(pB0), mB1 = __ballot(pB1);
            if (pA0) { int s = cntA + __popcll(mA0 & ltmask); if (s < 512) sidx[wv][0][s] = (unsigned short)j0; }
            cntA += __popcll(mA0);
            if (pA1) { int s = cntA + __popcll(mA1 & ltmask); if (s < 512) sidx[wv][0][s] = (unsigned short)(j0 + 1); }
            cntA += __popcll(mA1);
            if (pB0) { int s = cntB + __popcll(mB0 & ltmask); if (s < 512) sidx[wv][1][s] = (unsigned short)j0; }
            cntB += __popcll(mB0);
            if (pB1) { int s = cntB + __popcll(mB1 & ltmask); if (s < 512) sidx[wv][1][s] = (unsigned short)(j0 + 1); }
            cntB += __popcll(mB1);
        }
        if (cntA > 512) cntA = 512;
        if (cntB > 512) cntB = 512;
        int cpadA = (cntA + 15) & ~15, cpadB = (cntB + 15) & ~15;   // pad to x16
        if (cpadA > 512) cpadA = 512;
        if (cpadB > 512) cpadB = 512;
        if (lane < cpadA - cntA) sidx[wv][0][cntA + lane] = (unsigned short)N_AG;
        if (lane < cpadB - cntB) sidx[wv][1][cntB + lane] = (unsigned short)N_AG;

        int d0 = lane * 2;
#pragma unroll
        for (int rep = 0; rep < 2; rep++) {      // 16-deep f16 gather
            int cpad = rep ? cpadB : cpadA;
            float s0 = 0.f, s1 = 0.f;
            for (int t2 = 0; t2 < cpad; t2 += 16) {
                f16x2 v[16];
#pragma unroll
                for (int r = 0; r < 16; r++) {
                    int j = sidx[wv][rep][t2 + r];
                    v[r] = *(const f16x2*)(h16In + (size_t)j * HDIM + d0);
                }
#pragma unroll
                for (int r = 0; r < 16; r++) { s0 += (float)v[r][0]; s1 += (float)v[r][1]; }
            }
            shs[2 * wv + rep][d0]     = s0;
            shs[2 * wv + rep][d0 + 1] = s1;
        }
    }
    __syncthreads();

    // ---- stage x = [emb(pp) | shs | hIn] as split-f16 fragments ----
    for (int u = tid; u < 16 * (KTOT / 8); u += 512) {   // 640 units
        int a = u & 15, kg = u >> 4;
        int ga = a0 + a;
        int k0 = kg * 8;
        float v[8];
        if (k0 < EDIM) {
            float px = pp[ga * 2], py = pp[ga * 2 + 1];
#pragma unroll
            for (int j = 0; j < 8; j++) {
                int k = k0 + j;
                v[j] = fmaf(px, We[k * 2], fmaf(py, We[k * 2 + 1], be[k]));
            }
        } else if (k0 < EDIM + HDIM) {
#pragma unroll
            for (int j = 0; j < 8; j++)
                v[j] = firstStep ? 0.f : shs[a][k0 - EDIM + j];
        } else {
#pragma unroll
            for (int j = 0; j < 8; j++)
                v[j] = hIn[(unsigned)ga * HDIM + (k0 - EDIM - HDIM + j)];
        }
        f16x8 hi8, lo8;
#pragma unroll
        for (int j = 0; j < 8; j++) {
            _Float16 hv = (_Float16)v[j];
            hi8[j] = hv;
            lo8[j] = (_Float16)((v[j] - (float)hv) * LOSCALE);
        }
        int ki = kg >> 2, ln = a | ((kg & 3) << 4);
        *(f16x8*)&AH[ki][ln][0] = hi8;
        *(f16x8*)&AL[ki][ln][0] = lo8;
    }
    __syncthreads();

    // ---- MFMA gates GEMM: wave wv owns ntiles {wv, wv+8, wv+16, wv+24} ----
    int dcol = wv * 16 + (lane & 15);

    f32x4 acc[4], accL[4];
#pragma unroll
    for (int g = 0; g < 4; g++) {
        float bb = bsum[dcol + g * 128];
        f32x4 z; z[0] = bb; z[1] = bb; z[2] = bb; z[3] = bb;
        acc[g] = z;
        f32x4 zz; zz[0] = 0.f; zz[1] = 0.f; zz[2] = 0.f; zz[3] = 0.f;
        accL[g] = zz;
    }
#pragma unroll
    for (int ki = 0; ki < KI; ki++) {
        f16x8 ah = *(const f16x8*)&AH[ki][lane][0];
        f16x8 al = *(const f16x8*)&AL[ki][lane][0];
#pragma unroll
        for (int g = 0; g < 4; g++) {
            int nt = wv + 8 * g;
            size_t off = (size_t)((nt * KI + ki) * 64 + lane) * 8;
            f16x8 bh = *(const f16x8*)&WfH[off];
            f16x8 bl = *(const f16x8*)&WfL[off];
            acc[g]  = __builtin_amdgcn_mfma_f32_16x16x32_f16(ah, bh, acc[g],  0, 0, 0);
            accL[g] = __builtin_amdgcn_mfma_f32_16x16x32_f16(al, bh, accL[g], 0, 0, 0);
            accL[g] = __builtin_amdgcn_mfma_f32_16x16x32_f16(ah, bl, accL[g], 0, 0, 0);
        }
    }

    // ---- LSTM pointwise update in registers; write hOut/h16Out, hs to LDS ----
    const float inv = 1.0f / LOSCALE;
#pragma unroll
    for (int r = 0; r < 4; r++) {
        int alc = (lane >> 4) * 4 + r;      // C/D row mapping
        int ga  = a0 + alc;
        float vi = fmaf(accL[0][r], inv, acc[0][r]);
        float vf = fmaf(accL[1][r], inv, acc[1][r]);
        float vg = fmaf(accL[2][r], inv, acc[2][r]);
        float vo = fmaf(accL[3][r], inv, acc[3][r]);
        float ig = 1.f / (1.f + expf(-vi));
        float fg = 1.f / (1.f + expf(-vf));
        float gg = tanhf(vg);
        float og = 1.f / (1.f + expf(-vo));
        float cold = c[(unsigned)ga * HDIM + dcol];
        float cn = fmaf(fg, cold, ig * gg);
        float hn = og * tanhf(cn);
        c[(unsigned)ga * HDIM + dcol]      = cn;
        hOut[(unsigned)ga * HDIM + dcol]   = hn;
        h16Out[(unsigned)ga * HDIM + dcol] = (_Float16)hn;
        hs[alc][dcol] = hn;                 // for fused decode (aliases sidx)
    }

    // ---- fused decoder tail: delta = h_new@Wd^T + bd; lastOut = lastIn + delta ----
    if (decStep >= 0) {
        __syncthreads();
        int ag = tid >> 5, comp = (tid >> 4) & 1, l16 = tid & 15;
        float s = 0.f;
#pragma unroll
        for (int j = 0; j < 8; j++) {
            int d = l16 * 8 + j;
            s += hs[ag][d] * Wd[comp * HDIM + d];
        }
        s += __shfl_down(s, 8, 16);
        s += __shfl_down(s, 4, 16);
        s += __shfl_down(s, 2, 16);
        s += __shfl_down(s, 1, 16);
        if (l16 == 0) {
            int ga = a0 + ag;
            float nl = lastIn[ga * 2 + comp] + s + bd[comp];
            lastOut[ga * 2 + comp] = nl;
            if (ga == 0) out[(8 + decStep) * 2 + comp] = nl;
        }
    }
}

extern "C" void kernel_launch(void* const* d_in, const int* in_sizes, int n_in,
                              void* d_out, int out_size, void* d_ws, size_t ws_size,
                              hipStream_t stream)
{
    const float* tracks = (const float*)d_in[0];
    const float* We     = (const float*)d_in[1];
    const float* be     = (const float*)d_in[2];
    const float* Wih    = (const float*)d_in[3];
    const float* Whh    = (const float*)d_in[4];
    const float* bih    = (const float*)d_in[5];
    const float* bhh    = (const float*)d_in[6];
    const float* Wd     = (const float*)d_in[7];
    const float* bd     = (const float*)d_in[8];
    float* out = (float*)d_out;
    float* ws  = (float*)d_ws;

    float*     hA     = ws;
    float*     hB     = ws + 524288;
    float*     c      = ws + 1048576;
    float*     lastA  = ws + 1572864;
    float*     lastB  = ws + 1581056;
    float*     bsum   = ws + 1589248;
    float*     posAll = ws + 1589760;
    _Float16*  WfH    = (_Float16*)(ws + 1647104);
    _Float16*  WfL    = (_Float16*)(ws + 1729024);
    float*     h16Af  = ws + 1810944;
    float*     h16Bf  = ws + 2073152;

    float*    hbuf[2]   = { hA, hB };
    _Float16* h16buf[2] = { (_Float16*)h16Af, (_Float16*)h16Bf };
    float*    lbuf[2]   = { lastA, lastB };

    init_kernel<<<2048, 256, 0, stream>>>(tracks, Wih, Whh, bih, bhh,
                                          hA, hB, c, lastA, lastB,
                                          WfH, WfL, bsum, posAll,
                                          h16Af, h16Bf, out);

    int k = 0;   // step counter: step k reads buf[(k+1)&1], writes buf[k&1]
    auto step = [&](const float* pp, const float* lin, float* lout,
                    int fs, int ds) {
        social_step<<<256, 512, 0, stream>>>(
            pp, We, be, WfH, WfL, bsum,
            hbuf[(k + 1) & 1], hbuf[k & 1],
            h16buf[(k + 1) & 1], h16buf[k & 1],
            c, lin, lout, Wd, bd, out, fs, ds);
        k++;
    };

    // step 0: x0 = [emb(tracks[:,0]) | zeros], h=c=0
    step(posAll, nullptr, nullptr, 1, -1);

    // encoder: t = 0..6 (pool over posAll[t], emb(posAll[t]))
    for (int t = 0; t < T_IN - 1; t++)
        step(posAll + (size_t)t * N_AG * 2, nullptr, nullptr, 0, -1);

    // decoder: 12 steps (pool+emb over lastIn; decode writes lastOut)
    for (int s = 0; s < PRELEN; s++)
        step(lbuf[s & 1], lbuf[s & 1], lbuf[(s + 1) & 1], 0, s);
}

// Round 17
// 446.087 us; speedup vs baseline: 1.6462x; 1.1413x over previous
//
#include <hip/hip_runtime.h>
#include <hip/hip_bf16.h>

#define N_AG   4096
#define T_IN   8
#define PRELEN 12
#define EDIM   64
#define HDIM   128
#define KTOT   320    // E + H (sh) + H (h)
#define GDIM   512    // 4*H
#define KI     10     // KTOT / 32
#define LOSCALE 2048.0f

typedef _Float16 f16x8 __attribute__((ext_vector_type(8)));
typedef _Float16 f16x2 __attribute__((ext_vector_type(2)));
typedef float    f32x4 __attribute__((ext_vector_type(4)));

// ---------------- workspace layout (float units) ----------------
// hA     @ 0        (524288)   h double buffer (f32)
// hB     @ 524288   (524288)
// c      @ 1048576  (524288)   block-private -> single buffer
// lastA  @ 1572864  (8192)     last double buffer
// lastB  @ 1581056  (8192)
// bsum   @ 1589248  (512)
// posAll @ 1589760  (57344)
// WfH    @ 1647104  (81920 floats = 163840 f16)
// WfL    @ 1729024  (81920 floats = 163840 f16)
// h16A   @ 1810944  (262208 floats = 4097x128 f16, row 4096 = zeros)
// h16B   @ 2073152  (262208)

// ---------------- init (verified, unchanged) ----------------
__global__ __launch_bounds__(256) void init_kernel(
    const float* __restrict__ tracks,
    const float* __restrict__ Wih, const float* __restrict__ Whh,
    const float* __restrict__ bih, const float* __restrict__ bhh,
    float* __restrict__ hA, float* __restrict__ hB, float* __restrict__ c,
    float* __restrict__ lastA, float* __restrict__ lastB,
    _Float16* __restrict__ WfH, _Float16* __restrict__ WfL,
    float* __restrict__ bsum, float* __restrict__ posAll,
    float* __restrict__ h16Af, float* __restrict__ h16Bf,
    float* __restrict__ out)
{
    int idx = blockIdx.x * 256 + threadIdx.x;   // grid covers 524288
    hA[idx] = 0.f;
    hB[idx] = 0.f;
    c[idx]  = 0.f;
    if (idx < 262208) { h16Af[idx] = 0.f; h16Bf[idx] = 0.f; }  // incl. pad row
    if (idx < KTOT * GDIM) {                    // pack W into MFMA fragment order, split f16
        int g = idx / KTOT, k = idx - g * KTOT;
        float val = (k < 192) ? Wih[g * 192 + k] : Whh[g * 128 + (k - 192)];
        int nt = g >> 4, ki = k >> 5;
        int ln = (g & 15) | (((k >> 3) & 3) << 4);
        int e  = k & 7;
        size_t off = (size_t)((nt * KI + ki) * 64 + ln) * 8 + e;
        _Float16 hi = (_Float16)val;
        WfH[off] = hi;
        WfL[off] = (_Float16)((val - (float)hi) * LOSCALE);
    }
    if (idx < N_AG) {                           // last = tracks[:, 7]
        lastA[idx * 2 + 0] = tracks[idx * 16 + 14];
        lastA[idx * 2 + 1] = tracks[idx * 16 + 15];
        lastB[idx * 2 + 0] = 0.f;
        lastB[idx * 2 + 1] = 0.f;
    }
    if (idx < GDIM) bsum[idx] = bih[idx] + bhh[idx];
    if (idx < 16)  out[idx] = tracks[idx];      // out[0:8] = tracks[0]
    if (idx < 7 * N_AG) {                       // posAll[t][a] = tracks[a, t]
        int t = idx / N_AG, a = idx & (N_AG - 1);
        posAll[idx * 2 + 0] = tracks[a * 16 + t * 2 + 0];
        posAll[idx * 2 + 1] = tracks[a * 16 + t * 2 + 1];
    }
}

// ---------------- fused per-step kernel, 16 waves (4/SIMD) ----------------
// 256 blocks x 1024 thr. Block owns 16 agents x ALL 512 gate cols.
// Pool: 1 agent/wave (LDS-staged scan, 16-deep gather).
// GEMM: K-split — wave (q, half) does ki in [5*half, 5*half+5) for ntiles
// {q, q+8, q+16, q+24}; half=1 dumps folded partials to LDS, half=0 combines
// and runs the pointwise epilogue. h/h16/last double-buffered by step parity.
__global__ void __launch_bounds__(1024, 1) social_step(
    const float* __restrict__ pp,       // positions for pool+emb (posAll[t] or lastIn)
    const float* __restrict__ We, const float* __restrict__ be,
    const _Float16* __restrict__ WfH, const _Float16* __restrict__ WfL,
    const float* __restrict__ bsum,
    const float* __restrict__ hIn, float* __restrict__ hOut,
    const _Float16* __restrict__ h16In, _Float16* __restrict__ h16Out,
    float* __restrict__ c,
    const float* __restrict__ lastIn, float* __restrict__ lastOut,
    const float* __restrict__ Wd, const float* __restrict__ bd,
    float* __restrict__ out,
    int firstStep, int decStep)
{
    __shared__ __align__(16) char smraw[77824];
    _Float16 (*AH)[64][8] = (_Float16(*)[64][8])smraw;              // 10 KB [KI][64][8]
    _Float16 (*AL)[64][8] = (_Float16(*)[64][8])(smraw + 10240);    // 10 KB
    float (*shs)[HDIM]    = (float(*)[HDIM])(smraw + 20480);        //  8 KB [16][128]
    unsigned short (*sidx)[512] = (unsigned short(*)[512])(smraw + 28672); // 16 KB [16][512]
    float (*hs)[HDIM]     = (float(*)[HDIM])(smraw + 28672);        //  8 KB (aliases sidx)
    float* posl           = (float*)(smraw + 45056);                // 32 KB [4096][2]
    float* accx           = (float*)(smraw + 45056);                // 32 KB (aliases posl)

    int tid  = threadIdx.x;
    int lane = tid & 63;
    int wv   = tid >> 6;                 // 0..15
    int a0   = blockIdx.x * 16;

    // ---- pool phase: wave wv owns agent a0+wv ----
    if (!firstStep) {
        // stage all positions into LDS (1024 thr x 2 x float4 = 32KB)
#pragma unroll
        for (int k = 0; k < 2; k++) {
            int u = tid + k * 1024;
            *(f32x4*)&posl[u * 4] = *(const f32x4*)(pp + (size_t)u * 4);
        }
        __syncthreads();

        const float2* pvl = (const float2*)posl;
        float2 pi = pvl[a0 + wv];
        unsigned long long ltmask = (1ull << lane) - 1ull;
        int cnt = 0;
#pragma unroll 8
        for (int cc = 0; cc < 32; cc++) {        // 128 candidates/iter, 2 ballots
            int j0 = cc * 128 + 2 * lane;
            float4 q4 = *(const float4*)&posl[(size_t)j0 * 2];
            float dx0 = q4.x - pi.x, dy0 = q4.y - pi.y;
            float dx1 = q4.z - pi.x, dy1 = q4.w - pi.y;
            bool p0 = dx0 * dx0 + dy0 * dy0 < 25.0f;
            bool p1 = dx1 * dx1 + dy1 * dy1 < 25.0f;
            unsigned long long m0 = __ballot(p0), m1 = __ballot(p1);
            if (p0) { int s = cnt + __popcll(m0 & ltmask); if (s < 512) sidx[wv][s] = (unsigned short)j0; }
            cnt += __popcll(m0);
            if (p1) { int s = cnt + __popcll(m1 & ltmask); if (s < 512) sidx[wv][s] = (unsigned short)(j0 + 1); }
            cnt += __popcll(m1);
        }
        if (cnt > 512) cnt = 512;
        int cpad = (cnt + 15) & ~15;
        if (cpad > 512) cpad = 512;
        if (lane < cpad - cnt) sidx[wv][cnt + lane] = (unsigned short)N_AG;

        int d0 = lane * 2;
        float s0 = 0.f, s1 = 0.f;
        for (int t2 = 0; t2 < cpad; t2 += 16) {  // 16-deep f16 gather
            f16x2 v[16];
#pragma unroll
            for (int r = 0; r < 16; r++) {
                int j = sidx[wv][t2 + r];
                v[r] = *(const f16x2*)(h16In + (size_t)j * HDIM + d0);
            }
#pragma unroll
            for (int r = 0; r < 16; r++) { s0 += (float)v[r][0]; s1 += (float)v[r][1]; }
        }
        shs[wv][d0]     = s0;
        shs[wv][d0 + 1] = s1;
    }
    __syncthreads();

    // ---- stage x = [emb(pp) | shs | hIn] as split-f16 fragments ----
    for (int u = tid; u < 16 * (KTOT / 8); u += 1024) {   // 640 units
        int a = u & 15, kg = u >> 4;
        int ga = a0 + a;
        int k0 = kg * 8;
        float v[8];
        if (k0 < EDIM) {
            float px = pp[ga * 2], py = pp[ga * 2 + 1];
#pragma unroll
            for (int j = 0; j < 8; j++) {
                int k = k0 + j;
                v[j] = fmaf(px, We[k * 2], fmaf(py, We[k * 2 + 1], be[k]));
            }
        } else if (k0 < EDIM + HDIM) {
#pragma unroll
            for (int j = 0; j < 8; j++)
                v[j] = firstStep ? 0.f : shs[a][k0 - EDIM + j];
        } else {
#pragma unroll
            for (int j = 0; j < 8; j++)
                v[j] = hIn[(unsigned)ga * HDIM + (k0 - EDIM - HDIM + j)];
        }
        f16x8 hi8, lo8;
#pragma unroll
        for (int j = 0; j < 8; j++) {
            _Float16 hv = (_Float16)v[j];
            hi8[j] = hv;
            lo8[j] = (_Float16)((v[j] - (float)hv) * LOSCALE);
        }
        int ki = kg >> 2, ln = a | ((kg & 3) << 4);
        *(f16x8*)&AH[ki][ln][0] = hi8;
        *(f16x8*)&AL[ki][ln][0] = lo8;
    }
    __syncthreads();

    // ---- MFMA gates GEMM, K-split across wave halves ----
    int q    = wv & 7;
    int half = wv >> 3;
    int dcol = q * 16 + (lane & 15);
    const float inv = 1.0f / LOSCALE;

    f32x4 acc[4], accL[4];
#pragma unroll
    for (int g = 0; g < 4; g++) {
        float bb = half ? 0.f : bsum[dcol + g * 128];
        f32x4 z; z[0] = bb; z[1] = bb; z[2] = bb; z[3] = bb;
        acc[g] = z;
        f32x4 zz; zz[0] = 0.f; zz[1] = 0.f; zz[2] = 0.f; zz[3] = 0.f;
        accL[g] = zz;
    }
#pragma unroll
    for (int kk = 0; kk < 5; kk++) {
        int ki = half * 5 + kk;
        f16x8 ah = *(const f16x8*)&AH[ki][lane][0];
        f16x8 al = *(const f16x8*)&AL[ki][lane][0];
#pragma unroll
        for (int g = 0; g < 4; g++) {
            int nt = q + 8 * g;
            size_t off = (size_t)((nt * KI + ki) * 64 + lane) * 8;
            f16x8 bh = *(const f16x8*)&WfH[off];
            f16x8 bl = *(const f16x8*)&WfL[off];
            acc[g]  = __builtin_amdgcn_mfma_f32_16x16x32_f16(ah, bh, acc[g],  0, 0, 0);
            accL[g] = __builtin_amdgcn_mfma_f32_16x16x32_f16(al, bh, accL[g], 0, 0, 0);
            accL[g] = __builtin_amdgcn_mfma_f32_16x16x32_f16(ah, bl, accL[g], 0, 0, 0);
        }
    }
    // fold lo term; half=1 exports partials to LDS (aliases dead posl)
#pragma unroll
    for (int g = 0; g < 4; g++) {
#pragma unroll
        for (int r = 0; r < 4; r++)
            acc[g][r] = fmaf(accL[g][r], inv, acc[g][r]);
    }
    if (half) {
#pragma unroll
        for (int g = 0; g < 4; g++)
            *(f32x4*)&accx[(size_t)((q * 4 + g) * 64 + lane) * 4] = acc[g];
    }
    __syncthreads();

    // ---- half=0 combines + LSTM pointwise update in registers ----
    if (!half) {
#pragma unroll
        for (int g = 0; g < 4; g++) {
            f32x4 o = *(const f32x4*)&accx[(size_t)((q * 4 + g) * 64 + lane) * 4];
#pragma unroll
            for (int r = 0; r < 4; r++) acc[g][r] += o[r];
        }
#pragma unroll
        for (int r = 0; r < 4; r++) {
            int alc = (lane >> 4) * 4 + r;      // C/D row mapping
            int ga  = a0 + alc;
            float vi = acc[0][r], vf = acc[1][r], vg = acc[2][r], vo = acc[3][r];
            float ig = 1.f / (1.f + expf(-vi));
            float fg = 1.f / (1.f + expf(-vf));
            float gg = tanhf(vg);
            float og = 1.f / (1.f + expf(-vo));
            float cold = c[(unsigned)ga * HDIM + dcol];
            float cn = fmaf(fg, cold, ig * gg);
            float hn = og * tanhf(cn);
            c[(unsigned)ga * HDIM + dcol]      = cn;
            hOut[(unsigned)ga * HDIM + dcol]   = hn;
            h16Out[(unsigned)ga * HDIM + dcol] = (_Float16)hn;
            hs[alc][dcol] = hn;                 // for fused decode (aliases sidx)
        }
    }

    // ---- fused decoder tail: delta = h_new@Wd^T + bd; lastOut = lastIn + delta ----
    if (decStep >= 0) {
        __syncthreads();
        if (tid < 512) {
            int ag = tid >> 5, comp = (tid >> 4) & 1, l16 = tid & 15;
            float s = 0.f;
#pragma unroll
            for (int j = 0; j < 8; j++) {
                int d = l16 * 8 + j;
                s += hs[ag][d] * Wd[comp * HDIM + d];
            }
            s += __shfl_down(s, 8, 16);
            s += __shfl_down(s, 4, 16);
            s += __shfl_down(s, 2, 16);
            s += __shfl_down(s, 1, 16);
            if (l16 == 0) {
                int ga = a0 + ag;
                float nl = lastIn[ga * 2 + comp] + s + bd[comp];
                lastOut[ga * 2 + comp] = nl;
                if (ga == 0) out[(8 + decStep) * 2 + comp] = nl;
            }
        }
    }
}

extern "C" void kernel_launch(void* const* d_in, const int* in_sizes, int n_in,
                              void* d_out, int out_size, void* d_ws, size_t ws_size,
                              hipStream_t stream)
{
    const float* tracks = (const float*)d_in[0];
    const float* We     = (const float*)d_in[1];
    const float* be     = (const float*)d_in[2];
    const float* Wih    = (const float*)d_in[3];
    const float* Whh    = (const float*)d_in[4];
    const float* bih    = (const float*)d_in[5];
    const float* bhh    = (const float*)d_in[6];
    const float* Wd     = (const float*)d_in[7];
    const float* bd     = (const float*)d_in[8];
    float* out = (float*)d_out;
    float* ws  = (float*)d_ws;

    float*     hA     = ws;
    float*     hB     = ws + 524288;
    float*     c      = ws + 1048576;
    float*     lastA  = ws + 1572864;
    float*     lastB  = ws + 1581056;
    float*     bsum   = ws + 1589248;
    float*     posAll = ws + 1589760;
    _Float16*  WfH    = (_Float16*)(ws + 1647104);
    _Float16*  WfL    = (_Float16*)(ws + 1729024);
    float*     h16Af  = ws + 1810944;
    float*     h16Bf  = ws + 2073152;

    float*    hbuf[2]   = { hA, hB };
    _Float16* h16buf[2] = { (_Float16*)h16Af, (_Float16*)h16Bf };
    float*    lbuf[2]   = { lastA, lastB };

    init_kernel<<<2048, 256, 0, stream>>>(tracks, Wih, Whh, bih, bhh,
                                          hA, hB, c, lastA, lastB,
                                          WfH, WfL, bsum, posAll,
                                          h16Af, h16Bf, out);

    int k = 0;   // step counter: step k reads buf[(k+1)&1], writes buf[k&1]
    auto step = [&](const float* pp, const float* lin, float* lout,
                    int fs, int ds) {
        social_step<<<256, 1024, 0, stream>>>(
            pp, We, be, WfH, WfL, bsum,
            hbuf[(k + 1) & 1], hbuf[k & 1],
            h16buf[(k + 1) & 1], h16buf[k & 1],
            c, lin, lout, Wd, bd, out, fs, ds);
        k++;
    };

    // step 0: x0 = [emb(tracks[:,0]) | zeros], h=c=0
    step(posAll, nullptr, nullptr, 1, -1);

    // encoder: t = 0..6 (pool over posAll[t], emb(posAll[t]))
    for (int t = 0; t < T_IN - 1; t++)
        step(posAll + (size_t)t * N_AG * 2, nullptr, nullptr, 0, -1);

    // decoder: 12 steps (pool+emb over lastIn; decode writes lastOut)
    for (int s = 0; s < PRELEN; s++)
        step(lbuf[s & 1], lbuf[s & 1], lbuf[(s + 1) & 1], 0, s);
}